// Round 11
// baseline (103.888 us; speedup 1.0000x reference)
//
#include <hip/hip_runtime.h>
#include <hip/hip_bf16.h>

#define BB 8
#define SS 1024
#define EE 768
#define HH 12
#define DD 64
#define NT (BB*SS)

typedef __attribute__((ext_vector_type(8))) short bf16x8;
typedef __attribute__((ext_vector_type(4))) float f32x4;

__device__ __forceinline__ ushort f2bf(float f) {
  union { float f; unsigned u; } x; x.f = f;
  unsigned r = x.u + 0x7fffu + ((x.u >> 16) & 1u);
  return (ushort)(r >> 16);
}

// hardware packed f32x2 -> bf16x2 (RNE)
__device__ __forceinline__ unsigned cvtpk(float a, float b) {
  unsigned r;
  asm("v_cvt_pk_bf16_f32 %0, %1, %2" : "=v"(r) : "v"(a), "v"(b));
  return r;
}

__device__ __forceinline__ void gl2lds(const void* g, void* l) {
  __builtin_amdgcn_global_load_lds(
      (const __attribute__((address_space(1))) unsigned int*)g,
      (__attribute__((address_space(3))) unsigned int*)l, 16, 0, 0);
}

#define MFMA16(A, B, C) __builtin_amdgcn_mfma_f32_16x16x32_bf16((A), (B), (C), 0, 0, 0)

// ---------------- weight conversion (Wo only; QKV weights converted inline) ----------------
__global__ void cvt_weights(const float* __restrict__ Wo, ushort* __restrict__ Wob) {
  int i = blockIdx.x * blockDim.x + threadIdx.x;
  if (i < EE*EE) Wob[i] = f2bf(Wo[i]);
}

// ---------------- QKV projection (f32 weights inline-converted, packed 8B stores) ----------
// Q,K out: [B,H,S,D] bf16 (Q pre-scaled by log2(e)/8 -> softmax in exp2 domain).
//   Swapped operands mfma(W, X): lane lr owns srow, d = f*16+lg*4+j -> ushort4 stores.
// V out: [B,H,D,S] bf16, transposed + sigma-permuted per 64-k tile (lane-linear granules
//   for attention's PV): pos = base + 32*(w>>1) + 8*lg + 4*(w&1) + j.
__global__ __launch_bounds__(256) void proj_qkv(
    const float* __restrict__ q, const float* __restrict__ k, const float* __restrict__ v,
    const float* __restrict__ Wq, const float* __restrict__ Wk, const float* __restrict__ Wv,
    ushort* __restrict__ Qb, ushort* __restrict__ Kb, ushort* __restrict__ Vt) {
  int bid = blockIdx.x;
  int m  = bid / (BB*HH*(SS/64));
  int r  = bid % (BB*HH*(SS/64));
  int bh = r / (SS/64);
  int st = r % (SS/64);

  const float* x = (m==0 ? q : (m==1 ? k : v)) + ((size_t)((bh/HH)*SS + st*64))*EE + (bh%HH)*DD;
  const float* W = (m==0 ? Wq : (m==1 ? Wk : Wv)) + (bh%HH)*DD*DD;

  int tid = threadIdx.x;
  int w = tid >> 6, l = tid & 63;
  int lr = l & 15, lg = l >> 4;

  // X fragments: row w*16+lr, k = ks*32 + lg*8 + e
  union { bf16x8 v; unsigned u[4]; } a[2];
  const float* xr = x + (size_t)(w*16 + lr)*EE;
#pragma unroll
  for (int ks = 0; ks < 2; ++ks) {
    f32x4 t0 = *(const f32x4*)(xr + ks*32 + lg*8);
    f32x4 t1 = *(const f32x4*)(xr + ks*32 + lg*8 + 4);
    a[ks].u[0] = cvtpk(t0[0], t0[1]); a[ks].u[1] = cvtpk(t0[2], t0[3]);
    a[ks].u[2] = cvtpk(t1[0], t1[1]); a[ks].u[3] = cvtpk(t1[2], t1[3]);
  }

  f32x4 acc[4] = {};
  if (m == 2) {
    // V: original order mfma(X, W) -> C[row=srow][col=d]
#pragma unroll
    for (int f = 0; f < 4; ++f) {
      const float* wr = W + (f*16 + lr)*DD + lg*8;
      union { bf16x8 v; unsigned u[4]; } b0, b1;
      f32x4 u0 = *(const f32x4*)(wr);      f32x4 u1 = *(const f32x4*)(wr + 4);
      f32x4 u2 = *(const f32x4*)(wr + 32); f32x4 u3 = *(const f32x4*)(wr + 36);
      b0.u[0] = cvtpk(u0[0], u0[1]); b0.u[1] = cvtpk(u0[2], u0[3]);
      b0.u[2] = cvtpk(u1[0], u1[1]); b0.u[3] = cvtpk(u1[2], u1[3]);
      b1.u[0] = cvtpk(u2[0], u2[1]); b1.u[1] = cvtpk(u2[2], u2[3]);
      b1.u[2] = cvtpk(u3[0], u3[1]); b1.u[3] = cvtpk(u3[2], u3[3]);
      acc[f] = MFMA16(a[0].v, b0.v, acc[f]);
      acc[f] = MFMA16(a[1].v, b1.v, acc[f]);
    }
    int posb = st*64 + 32*(w>>1) + 8*lg + 4*(w&1);
#pragma unroll
    for (int f = 0; f < 4; ++f) {
      ushort2 p0, p1;
      *(unsigned*)&p0 = cvtpk(acc[f][0], acc[f][1]);
      *(unsigned*)&p1 = cvtpk(acc[f][2], acc[f][3]);
      ushort4 pk; pk.x = p0.x; pk.y = p0.y; pk.z = p1.x; pk.w = p1.y;
      *(ushort4*)(Vt + ((size_t)bh*DD + f*16 + lr)*SS + posb) = pk;
    }
  } else {
    // Q/K: swapped order mfma(W, X) -> C[row=d][col=srow]
#pragma unroll
    for (int f = 0; f < 4; ++f) {
      const float* wr = W + (f*16 + lr)*DD + lg*8;
      union { bf16x8 v; unsigned u[4]; } b0, b1;
      f32x4 u0 = *(const f32x4*)(wr);      f32x4 u1 = *(const f32x4*)(wr + 4);
      f32x4 u2 = *(const f32x4*)(wr + 32); f32x4 u3 = *(const f32x4*)(wr + 36);
      b0.u[0] = cvtpk(u0[0], u0[1]); b0.u[1] = cvtpk(u0[2], u0[3]);
      b0.u[2] = cvtpk(u1[0], u1[1]); b0.u[3] = cvtpk(u1[2], u1[3]);
      b1.u[0] = cvtpk(u2[0], u2[1]); b1.u[1] = cvtpk(u2[2], u2[3]);
      b1.u[2] = cvtpk(u3[0], u3[1]); b1.u[3] = cvtpk(u3[2], u3[3]);
      acc[f] = MFMA16(b0.v, a[0].v, acc[f]);
      acc[f] = MFMA16(b1.v, a[1].v, acc[f]);
    }
    float qscale = (m == 0) ? 0.18033688011112042f : 1.0f;  // 0.125*log2(e)
    ushort* dst = (m == 0 ? Qb : Kb) + ((size_t)bh*SS + st*64 + w*16 + lr)*DD;
#pragma unroll
    for (int f = 0; f < 4; ++f) {
      ushort2 p0, p1;
      *(unsigned*)&p0 = cvtpk(acc[f][0]*qscale, acc[f][1]*qscale);
      *(unsigned*)&p1 = cvtpk(acc[f][2]*qscale, acc[f][3]*qscale);
      ushort4 pk; pk.x = p0.x; pk.y = p0.y; pk.z = p1.x; pk.w = p1.y;
      *(ushort4*)(dst + f*16 + lg*4) = pk;
    }
  }
}

// ---------------- flash attention (R9-verified structure) ----------------
// Block: one (b,h,qtile128). 4 waves x 32 q-rows (dual-Q). P = exp2(S') unshifted;
// normalize in epilogue. bh = bid % 96 -> blocks sharing K/V sit on one XCD.
// K and V staged as lane-linear 16B fragment granules (V pre-permuted by proj_qkv):
// conflict-free ds_read_b128. Depth-2 prefetch over 3 LDS buffers, counted vmcnt(4).
// Denominator l via all-ones-A MFMA (column sums of P, accumulated across tiles).
__global__ __launch_bounds__(256) void attn_fwd(
    const ushort* __restrict__ Qb, const ushort* __restrict__ Kb,
    const ushort* __restrict__ Vt, ushort* __restrict__ attn) {
  __shared__ uint4 ldsq[3072];     // 48 KiB: 3 buffers x (K 8KB + V 8KB)
  char* ldsb = (char*)ldsq;

  int bid = blockIdx.x;
  int bh = bid % (BB*HH);
  int qt = bid / (BB*HH);
  int b = bh / HH, h = bh % HH;
  int tid = threadIdx.x, w = tid >> 6, l = tid & 63;
  int lr = l & 15, lg = l >> 4;

  const ushort* Qp0 = Qb + ((size_t)bh*SS + qt*128 + w*32 + lr)*DD;
  bf16x8 bq[2][2];
  bq[0][0] = *(const bf16x8*)(Qp0 + lg*8);
  bq[0][1] = *(const bf16x8*)(Qp0 + 32 + lg*8);
  bq[1][0] = *(const bf16x8*)(Qp0 + 16*DD + lg*8);
  bq[1][1] = *(const bf16x8*)(Qp0 + 16*DD + 32 + lg*8);

  const ushort* Kbh = Kb + (size_t)bh*SS*DD;
  const ushort* Vbh = Vt + (size_t)bh*DD*SS;

  const short ONE = (short)0x3F80;           // bf16 1.0
  bf16x8 ones = {ONE, ONE, ONE, ONE, ONE, ONE, ONE, ONE};

  f32x4 lsum[2] = {};              // every row = full denominator for col q=lr
  f32x4 o[2][4] = {};

#define STAGE(bufidx, kt) do {                                                   \
    char* LK_ = ldsb + (bufidx)*16384;                                           \
    const ushort* ksrc = Kbh + ((size_t)((kt)*64 + w*16 + lr))*DD + lg*8;        \
    const ushort* vsrc = Vbh + ((size_t)(w*16 + lr))*SS + (kt)*64 + lg*8;        \
    gl2lds(ksrc,      LK_ + tid*16);                                             \
    gl2lds(ksrc + 32, LK_ + 4096 + tid*16);                                      \
    gl2lds(vsrc,      LK_ + 8192 + tid*16);                                      \
    gl2lds(vsrc + 32, LK_ + 12288 + tid*16);                                     \
  } while (0)

  STAGE(0, 0);
  STAGE(1, 1);
  int bi = 0;
  for (int kt = 0; kt < 16; ++kt) {
    const char* LK_ = ldsb + bi*16384;
    const char* LV_ = LK_ + 8192;

    // tile kt landed (4 oldest loads); tile kt+1's 4 may remain in flight
    if (kt < 15) { asm volatile("s_waitcnt vmcnt(4)" ::: "memory"); }
    else         { asm volatile("s_waitcnt vmcnt(0)" ::: "memory"); }
    __builtin_amdgcn_s_barrier();
    __builtin_amdgcn_sched_barrier(0);

    // stage tile kt+2 into the buffer last read at iter kt-1 (safe: readers done)
    int pi = bi + 2; if (pi >= 3) pi -= 3;
    if (kt < 14) STAGE(pi, kt + 2);

    f32x4 st0[4] = {}, st1[4] = {};
    __builtin_amdgcn_s_setprio(1);
#pragma unroll
    for (int f = 0; f < 4; ++f) {
      bf16x8 k0 = *(const bf16x8*)(LK_ + f*1024 + l*16);
      bf16x8 k1 = *(const bf16x8*)(LK_ + 4096 + f*1024 + l*16);
      st0[f] = MFMA16(k0, bq[0][0], st0[f]);
      st0[f] = MFMA16(k1, bq[0][1], st0[f]);
      st1[f] = MFMA16(k0, bq[1][0], st1[f]);
      st1[f] = MFMA16(k1, bq[1][1], st1[f]);
    }
    __builtin_amdgcn_s_setprio(0);

    union { bf16x8 v; unsigned u[4]; } pba[2], pbb[2];
#pragma unroll
    for (int s = 0; s < 2; ++s) {
      f32x4* st = (s == 0) ? st0 : st1;
#pragma unroll
      for (int f = 0; f < 4; ++f) {
#pragma unroll
        for (int j = 0; j < 4; ++j) st[f][j] = __builtin_amdgcn_exp2f(st[f][j]);
      }
      pba[s].u[0] = cvtpk(st[0][0], st[0][1]); pba[s].u[1] = cvtpk(st[0][2], st[0][3]);
      pba[s].u[2] = cvtpk(st[1][0], st[1][1]); pba[s].u[3] = cvtpk(st[1][2], st[1][3]);
      pbb[s].u[0] = cvtpk(st[2][0], st[2][1]); pbb[s].u[1] = cvtpk(st[2][2], st[2][3]);
      pbb[s].u[2] = cvtpk(st[3][0], st[3][1]); pbb[s].u[3] = cvtpk(st[3][2], st[3][3]);
    }

    __builtin_amdgcn_s_setprio(1);
#pragma unroll
    for (int f = 0; f < 4; ++f) {
      bf16x8 va = *(const bf16x8*)(LV_ + f*1024 + l*16);          // k-pos 0..31 (sigma)
      bf16x8 vc = *(const bf16x8*)(LV_ + 4096 + f*1024 + l*16);   // k-pos 32..63
      o[0][f] = MFMA16(va, pba[0].v, o[0][f]);
      o[0][f] = MFMA16(vc, pbb[0].v, o[0][f]);
      o[1][f] = MFMA16(va, pba[1].v, o[1][f]);
      o[1][f] = MFMA16(vc, pbb[1].v, o[1][f]);
    }
    // denominator: ones-row MFMA accumulates column sums of P
    lsum[0] = MFMA16(ones, pba[0].v, lsum[0]);
    lsum[0] = MFMA16(ones, pbb[0].v, lsum[0]);
    lsum[1] = MFMA16(ones, pba[1].v, lsum[1]);
    lsum[1] = MFMA16(ones, pbb[1].v, lsum[1]);
    __builtin_amdgcn_s_setprio(0);

    bi = (bi == 2) ? 0 : bi + 1;
  }
#undef STAGE

  // epilogue: lane lr already holds the full denominator for its q in lsum[s][*]
#pragma unroll
  for (int s = 0; s < 2; ++s) {
    float inv = 1.0f / lsum[s][0];
    ushort* orow = attn + ((size_t)(b*SS + qt*128 + w*32 + s*16 + lr))*EE + h*DD;
#pragma unroll
    for (int f = 0; f < 4; ++f) {
      ushort4 pkd;
      pkd.x = f2bf(o[s][f][0] * inv);
      pkd.y = f2bf(o[s][f][1] * inv);
      pkd.z = f2bf(o[s][f][2] * inv);
      pkd.w = f2bf(o[s][f][3] * inv);
      *(ushort4*)(orow + f*16 + lg*4) = pkd;
    }
  }
}

// ---------------- output projection (counted-vmcnt LDS-staged MFMA GEMM) ----------------
// Same-mt blocks congruent mod 8 -> same XCD. Two barriers/iter, vmcnt(6) counted:
// next tile's 6 loads stay in flight across bar1 (no drain-before-barrier stall).
__global__ __launch_bounds__(256) void out_proj(
    const ushort* __restrict__ attn, const ushort* __restrict__ Wob,
    const float* __restrict__ bo, float* __restrict__ out) {
  __shared__ uint4 ldsq[3072];   // 48 KiB: 2 buffers x (A 8KB + B 16KB)
  char* ldsb = (char*)ldsq;

  int bid = blockIdx.x;
  int mt = bid & 127;
  int nt = bid >> 7;
  int tid = threadIdx.x, w = tid >> 6, l = tid & 63;
  int lr = l & 15, lg = l >> 4;

  int rS = tid >> 3;
  int cSw = (((tid & 7) * 16) ^ ((rS & 7) << 4)) >> 1;

  const ushort* Abase = attn + ((size_t)mt*64)*EE;
  const ushort* Bbase = Wob + ((size_t)nt*128)*EE;

#define OSTAGE(bufidx, kt) do {                                                  \
    char* LA_ = ldsb + (bufidx)*24576;                                           \
    char* LB_ = LA_ + 8192;                                                      \
    const ushort* asrc = Abase + (kt)*64 + cSw;                                  \
    const ushort* bsrc = Bbase + (kt)*64 + cSw;                                  \
    gl2lds(asrc + (size_t)rS*EE,        LA_ + tid*16);                           \
    gl2lds(asrc + (size_t)(rS+32)*EE,   LA_ + 4096 + tid*16);                    \
    gl2lds(bsrc + (size_t)rS*EE,        LB_ + tid*16);                           \
    gl2lds(bsrc + (size_t)(rS+32)*EE,   LB_ + 4096 + tid*16);                    \
    gl2lds(bsrc + (size_t)(rS+64)*EE,   LB_ + 8192 + tid*16);                    \
    gl2lds(bsrc + (size_t)(rS+96)*EE,   LB_ + 12288 + tid*16);                   \
  } while (0)

  f32x4 acc[4][2] = {};

#define OCOMPUTE(bufidx) do {                                                    \
    const char* LA_ = ldsb + (bufidx)*24576;                                     \
    const char* LB_ = LA_ + 8192;                                                \
    bf16x8 af[4][2], bf[2][2];                                                   \
    _Pragma("unroll")                                                            \
    for (int f = 0; f < 4; ++f) {                                                \
      int row = f*16 + lr; int sw = (row & 7) << 4;                              \
      af[f][0] = *(const bf16x8*)(LA_ + row*128 + ((lg*16) ^ sw));               \
      af[f][1] = *(const bf16x8*)(LA_ + row*128 + ((64 + lg*16) ^ sw));          \
    }                                                                            \
    _Pragma("unroll")                                                            \
    for (int g = 0; g < 2; ++g) {                                                \
      int row = w*32 + g*16 + lr; int sw = (row & 7) << 4;                       \
      bf[g][0] = *(const bf16x8*)(LB_ + row*128 + ((lg*16) ^ sw));               \
      bf[g][1] = *(const bf16x8*)(LB_ + row*128 + ((64 + lg*16) ^ sw));          \
    }                                                                            \
    _Pragma("unroll")                                                            \
    for (int f = 0; f < 4; ++f) {                                                \
      _Pragma("unroll")                                                          \
      for (int g = 0; g < 2; ++g) {                                              \
        acc[f][g] = MFMA16(af[f][0], bf[g][0], acc[f][g]);                       \
        acc[f][g] = MFMA16(af[f][1], bf[g][1], acc[f][g]);                       \
      }                                                                          \
    }                                                                            \
  } while (0)

  OSTAGE(0, 0);
  for (int kt = 0; kt < EE/64; ++kt) {
    if (kt < EE/64 - 1) OSTAGE((kt + 1) & 1, kt + 1);
    if (kt < EE/64 - 1) { asm volatile("s_waitcnt vmcnt(6)" ::: "memory"); }
    else                { asm volatile("s_waitcnt vmcnt(0)" ::: "memory"); }
    __builtin_amdgcn_s_barrier();          // all waves' tile-kt loads landed
    __builtin_amdgcn_sched_barrier(0);
    OCOMPUTE(kt & 1);
    __builtin_amdgcn_s_barrier();          // reads done before next iter's OSTAGE
    __builtin_amdgcn_sched_barrier(0);
  }
#undef OSTAGE
#undef OCOMPUTE

#pragma unroll
  for (int g = 0; g < 2; ++g) {
    int col = nt*128 + w*32 + g*16 + lr;
    float bias = bo[col];
#pragma unroll
    for (int f = 0; f < 4; ++f) {
#pragma unroll
      for (int j = 0; j < 4; ++j) {
        int row = mt*64 + f*16 + lg*4 + j;
        out[(size_t)row*EE + col] = acc[f][g][j] + bias;
      }
    }
  }
}

extern "C" void kernel_launch(void* const* d_in, const int* in_sizes, int n_in,
                              void* d_out, int out_size, void* d_ws, size_t ws_size,
                              hipStream_t stream) {
  (void)in_sizes; (void)n_in; (void)out_size; (void)ws_size;
  const float* q  = (const float*)d_in[0];
  const float* k  = (const float*)d_in[1];
  const float* v  = (const float*)d_in[2];
  const float* Wq = (const float*)d_in[3];
  const float* Wk = (const float*)d_in[4];
  const float* Wv = (const float*)d_in[5];
  const float* Wo = (const float*)d_in[6];
  const float* bo = (const float*)d_in[7];
  float* out = (float*)d_out;

  char* ws = (char*)d_ws;
  const size_t SZ = (size_t)BB*HH*SS*DD*2;     // 12582912 bytes each
  ushort* Qb   = (ushort*)(ws);
  ushort* Kb   = (ushort*)(ws + SZ);
  ushort* Vt   = (ushort*)(ws + 2*SZ);
  ushort* attn = (ushort*)(ws + 3*SZ);
  ushort* Wob  = (ushort*)(ws + 4*SZ);

  cvt_weights<<<(EE*EE + 255)/256, 256, 0, stream>>>(Wo, Wob);
  proj_qkv<<<3*BB*HH*(SS/64), 256, 0, stream>>>(q, k, v, Wq, Wk, Wv, Qb, Kb, Vt);
  attn_fwd<<<BB*HH*(SS/128), 256, 0, stream>>>(Qb, Kb, Vt, attn);
  out_proj<<<(NT/64)*(EE/128), 256, 0, stream>>>(attn, Wob, bo, out);
}

// Round 12
// 89.809 us; speedup vs baseline: 1.1568x; 1.1568x over previous
//
#include <hip/hip_runtime.h>
#include <hip/hip_bf16.h>

#define BB 8
#define SS 1024
#define EE 768
#define HH 12
#define DD 64
#define NT (BB*SS)

typedef __attribute__((ext_vector_type(8))) short bf16x8;
typedef __attribute__((ext_vector_type(4))) float f32x4;

__device__ __forceinline__ ushort f2bf(float f) {
  union { float f; unsigned u; } x; x.f = f;
  unsigned r = x.u + 0x7fffu + ((x.u >> 16) & 1u);
  return (ushort)(r >> 16);
}

// hardware packed f32x2 -> bf16x2 (RNE)
__device__ __forceinline__ unsigned cvtpk(float a, float b) {
  unsigned r;
  asm("v_cvt_pk_bf16_f32 %0, %1, %2" : "=v"(r) : "v"(a), "v"(b));
  return r;
}

__device__ __forceinline__ void gl2lds(const void* g, void* l) {
  __builtin_amdgcn_global_load_lds(
      (const __attribute__((address_space(1))) unsigned int*)g,
      (__attribute__((address_space(3))) unsigned int*)l, 16, 0, 0);
}

#define MFMA16(A, B, C) __builtin_amdgcn_mfma_f32_16x16x32_bf16((A), (B), (C), 0, 0, 0)

// ---------------- weight conversion (all four weight matrices) ----------------
__global__ void cvt_weights(const float* __restrict__ Wq, const float* __restrict__ Wk,
                            const float* __restrict__ Wv, const float* __restrict__ Wo,
                            ushort* __restrict__ Wqb, ushort* __restrict__ Wkb,
                            ushort* __restrict__ Wvb, ushort* __restrict__ Wob) {
  int i = blockIdx.x * blockDim.x + threadIdx.x;
  const int NW = HH*DD*DD;           // 49152
  if (i < NW) { Wqb[i] = f2bf(Wq[i]); Wkb[i] = f2bf(Wk[i]); Wvb[i] = f2bf(Wv[i]); }
  if (i < EE*EE) Wob[i] = f2bf(Wo[i]);
}

// ---------------- QKV projection (bf16 weights, packed 8B stores) ----------
// Q,K out: [B,H,S,D] bf16 (Q pre-scaled by log2(e)/8 -> softmax in exp2 domain).
//   Swapped operands mfma(W, X): lane lr owns srow, d = f*16+lg*4+j -> ushort4 stores.
// V out: [B,H,D,S] bf16, transposed + sigma-permuted per 64-k tile (lane-linear granules
//   for attention's PV): pos = base + 32*(w>>1) + 8*lg + 4*(w&1) + j.
__global__ __launch_bounds__(256) void proj_qkv(
    const float* __restrict__ q, const float* __restrict__ k, const float* __restrict__ v,
    const ushort* __restrict__ Wqb, const ushort* __restrict__ Wkb, const ushort* __restrict__ Wvb,
    ushort* __restrict__ Qb, ushort* __restrict__ Kb, ushort* __restrict__ Vt) {
  int bid = blockIdx.x;
  int m  = bid / (BB*HH*(SS/64));
  int r  = bid % (BB*HH*(SS/64));
  int bh = r / (SS/64);
  int st = r % (SS/64);

  const float*  x = (m==0 ? q : (m==1 ? k : v)) + ((size_t)((bh/HH)*SS + st*64))*EE + (bh%HH)*DD;
  const ushort* W = (m==0 ? Wqb : (m==1 ? Wkb : Wvb)) + (bh%HH)*DD*DD;

  int tid = threadIdx.x;
  int w = tid >> 6, l = tid & 63;
  int lr = l & 15, lg = l >> 4;

  // X fragments: row w*16+lr, k = ks*32 + lg*8 + e
  union { bf16x8 v; unsigned u[4]; } a[2];
  const float* xr = x + (size_t)(w*16 + lr)*EE;
#pragma unroll
  for (int ks = 0; ks < 2; ++ks) {
    f32x4 t0 = *(const f32x4*)(xr + ks*32 + lg*8);
    f32x4 t1 = *(const f32x4*)(xr + ks*32 + lg*8 + 4);
    a[ks].u[0] = cvtpk(t0[0], t0[1]); a[ks].u[1] = cvtpk(t0[2], t0[3]);
    a[ks].u[2] = cvtpk(t1[0], t1[1]); a[ks].u[3] = cvtpk(t1[2], t1[3]);
  }

  f32x4 acc[4] = {};
  if (m == 2) {
    // V: original order mfma(X, W) -> C[row=srow][col=d]
#pragma unroll
    for (int f = 0; f < 4; ++f) {
      bf16x8 b0 = *(const bf16x8*)(W + (f*16 + lr)*DD + lg*8);
      bf16x8 b1 = *(const bf16x8*)(W + (f*16 + lr)*DD + 32 + lg*8);
      acc[f] = MFMA16(a[0].v, b0, acc[f]);
      acc[f] = MFMA16(a[1].v, b1, acc[f]);
    }
    int posb = st*64 + 32*(w>>1) + 8*lg + 4*(w&1);
#pragma unroll
    for (int f = 0; f < 4; ++f) {
      ushort2 p0, p1;
      *(unsigned*)&p0 = cvtpk(acc[f][0], acc[f][1]);
      *(unsigned*)&p1 = cvtpk(acc[f][2], acc[f][3]);
      ushort4 pk; pk.x = p0.x; pk.y = p0.y; pk.z = p1.x; pk.w = p1.y;
      *(ushort4*)(Vt + ((size_t)bh*DD + f*16 + lr)*SS + posb) = pk;
    }
  } else {
    // Q/K: swapped order mfma(W, X) -> C[row=d][col=srow]; lane lr owns one srow
#pragma unroll
    for (int f = 0; f < 4; ++f) {
      bf16x8 b0 = *(const bf16x8*)(W + (f*16 + lr)*DD + lg*8);
      bf16x8 b1 = *(const bf16x8*)(W + (f*16 + lr)*DD + 32 + lg*8);
      acc[f] = MFMA16(b0, a[0].v, acc[f]);
      acc[f] = MFMA16(b1, a[1].v, acc[f]);
    }
    float qscale = (m == 0) ? 0.18033688011112042f : 1.0f;  // 0.125*log2(e)
    ushort* dst = (m == 0 ? Qb : Kb) + ((size_t)bh*SS + st*64 + w*16 + lr)*DD;
#pragma unroll
    for (int f = 0; f < 4; ++f) {
      ushort2 p0, p1;
      *(unsigned*)&p0 = cvtpk(acc[f][0]*qscale, acc[f][1]*qscale);
      *(unsigned*)&p1 = cvtpk(acc[f][2]*qscale, acc[f][3]*qscale);
      ushort4 pk; pk.x = p0.x; pk.y = p0.y; pk.z = p1.x; pk.w = p1.y;
      *(ushort4*)(dst + f*16 + lg*4) = pk;
    }
  }
}

// ---------------- flash attention (R9-verified structure) ----------------
// Block: one (b,h,qtile128). 4 waves x 32 q-rows (dual-Q). P = exp2(S') unshifted;
// normalize in epilogue. bh = bid % 96 -> blocks sharing K/V sit on one XCD.
// K and V staged as lane-linear 16B fragment granules (V pre-permuted by proj_qkv):
// conflict-free ds_read_b128. Depth-2 prefetch over 3 LDS buffers, counted vmcnt(4).
// Denominator l via all-ones-A MFMA (column sums of P, accumulated across tiles).
__global__ __launch_bounds__(256) void attn_fwd(
    const ushort* __restrict__ Qb, const ushort* __restrict__ Kb,
    const ushort* __restrict__ Vt, ushort* __restrict__ attn) {
  __shared__ uint4 ldsq[3072];     // 48 KiB: 3 buffers x (K 8KB + V 8KB)
  char* ldsb = (char*)ldsq;

  int bid = blockIdx.x;
  int bh = bid % (BB*HH);
  int qt = bid / (BB*HH);
  int b = bh / HH, h = bh % HH;
  int tid = threadIdx.x, w = tid >> 6, l = tid & 63;
  int lr = l & 15, lg = l >> 4;

  const ushort* Qp0 = Qb + ((size_t)bh*SS + qt*128 + w*32 + lr)*DD;
  bf16x8 bq[2][2];
  bq[0][0] = *(const bf16x8*)(Qp0 + lg*8);
  bq[0][1] = *(const bf16x8*)(Qp0 + 32 + lg*8);
  bq[1][0] = *(const bf16x8*)(Qp0 + 16*DD + lg*8);
  bq[1][1] = *(const bf16x8*)(Qp0 + 16*DD + 32 + lg*8);

  const ushort* Kbh = Kb + (size_t)bh*SS*DD;
  const ushort* Vbh = Vt + (size_t)bh*DD*SS;

  const short ONE = (short)0x3F80;           // bf16 1.0
  bf16x8 ones = {ONE, ONE, ONE, ONE, ONE, ONE, ONE, ONE};

  f32x4 lsum[2] = {};              // every row = full denominator for col q=lr
  f32x4 o[2][4] = {};

#define STAGE(bufidx, kt) do {                                                   \
    char* LK_ = ldsb + (bufidx)*16384;                                           \
    const ushort* ksrc = Kbh + ((size_t)((kt)*64 + w*16 + lr))*DD + lg*8;        \
    const ushort* vsrc = Vbh + ((size_t)(w*16 + lr))*SS + (kt)*64 + lg*8;        \
    gl2lds(ksrc,      LK_ + tid*16);                                             \
    gl2lds(ksrc + 32, LK_ + 4096 + tid*16);                                      \
    gl2lds(vsrc,      LK_ + 8192 + tid*16);                                      \
    gl2lds(vsrc + 32, LK_ + 12288 + tid*16);                                     \
  } while (0)

  STAGE(0, 0);
  STAGE(1, 1);
  int bi = 0;
  for (int kt = 0; kt < 16; ++kt) {
    const char* LK_ = ldsb + bi*16384;
    const char* LV_ = LK_ + 8192;

    // tile kt landed (4 oldest loads); tile kt+1's 4 may remain in flight
    if (kt < 15) { asm volatile("s_waitcnt vmcnt(4)" ::: "memory"); }
    else         { asm volatile("s_waitcnt vmcnt(0)" ::: "memory"); }
    __builtin_amdgcn_s_barrier();
    __builtin_amdgcn_sched_barrier(0);

    // stage tile kt+2 into the buffer last read at iter kt-1 (safe: readers done)
    int pi = bi + 2; if (pi >= 3) pi -= 3;
    if (kt < 14) STAGE(pi, kt + 2);

    f32x4 st0[4] = {}, st1[4] = {};
    __builtin_amdgcn_s_setprio(1);
#pragma unroll
    for (int f = 0; f < 4; ++f) {
      bf16x8 k0 = *(const bf16x8*)(LK_ + f*1024 + l*16);
      bf16x8 k1 = *(const bf16x8*)(LK_ + 4096 + f*1024 + l*16);
      st0[f] = MFMA16(k0, bq[0][0], st0[f]);
      st0[f] = MFMA16(k1, bq[0][1], st0[f]);
      st1[f] = MFMA16(k0, bq[1][0], st1[f]);
      st1[f] = MFMA16(k1, bq[1][1], st1[f]);
    }
    __builtin_amdgcn_s_setprio(0);

    union { bf16x8 v; unsigned u[4]; } pba[2], pbb[2];
#pragma unroll
    for (int s = 0; s < 2; ++s) {
      f32x4* st = (s == 0) ? st0 : st1;
#pragma unroll
      for (int f = 0; f < 4; ++f) {
#pragma unroll
        for (int j = 0; j < 4; ++j) st[f][j] = __builtin_amdgcn_exp2f(st[f][j]);
      }
      pba[s].u[0] = cvtpk(st[0][0], st[0][1]); pba[s].u[1] = cvtpk(st[0][2], st[0][3]);
      pba[s].u[2] = cvtpk(st[1][0], st[1][1]); pba[s].u[3] = cvtpk(st[1][2], st[1][3]);
      pbb[s].u[0] = cvtpk(st[2][0], st[2][1]); pbb[s].u[1] = cvtpk(st[2][2], st[2][3]);
      pbb[s].u[2] = cvtpk(st[3][0], st[3][1]); pbb[s].u[3] = cvtpk(st[3][2], st[3][3]);
    }

    __builtin_amdgcn_s_setprio(1);
#pragma unroll
    for (int f = 0; f < 4; ++f) {
      bf16x8 va = *(const bf16x8*)(LV_ + f*1024 + l*16);          // k-pos 0..31 (sigma)
      bf16x8 vc = *(const bf16x8*)(LV_ + 4096 + f*1024 + l*16);   // k-pos 32..63
      o[0][f] = MFMA16(va, pba[0].v, o[0][f]);
      o[0][f] = MFMA16(vc, pbb[0].v, o[0][f]);
      o[1][f] = MFMA16(va, pba[1].v, o[1][f]);
      o[1][f] = MFMA16(vc, pbb[1].v, o[1][f]);
    }
    // denominator: ones-row MFMA accumulates column sums of P
    lsum[0] = MFMA16(ones, pba[0].v, lsum[0]);
    lsum[0] = MFMA16(ones, pbb[0].v, lsum[0]);
    lsum[1] = MFMA16(ones, pba[1].v, lsum[1]);
    lsum[1] = MFMA16(ones, pbb[1].v, lsum[1]);
    __builtin_amdgcn_s_setprio(0);

    bi = (bi == 2) ? 0 : bi + 1;
  }
#undef STAGE

  // epilogue: lane lr already holds the full denominator for its q in lsum[s][*]
#pragma unroll
  for (int s = 0; s < 2; ++s) {
    float inv = 1.0f / lsum[s][0];
    ushort* orow = attn + ((size_t)(b*SS + qt*128 + w*32 + s*16 + lr))*EE + h*DD;
#pragma unroll
    for (int f = 0; f < 4; ++f) {
      ushort4 pkd;
      pkd.x = f2bf(o[s][f][0] * inv);
      pkd.y = f2bf(o[s][f][1] * inv);
      pkd.z = f2bf(o[s][f][2] * inv);
      pkd.w = f2bf(o[s][f][3] * inv);
      *(ushort4*)(orow + f*16 + lg*4) = pkd;
    }
  }
}

// ---------------- output projection (counted-vmcnt LDS-staged MFMA GEMM) ----------------
// Same-mt blocks congruent mod 8 -> same XCD. Two barriers/iter, vmcnt(6) counted:
// next tile's 6 loads stay in flight across bar1 (no drain-before-barrier stall).
__global__ __launch_bounds__(256) void out_proj(
    const ushort* __restrict__ attn, const ushort* __restrict__ Wob,
    const float* __restrict__ bo, float* __restrict__ out) {
  __shared__ uint4 ldsq[3072];   // 48 KiB: 2 buffers x (A 8KB + B 16KB)
  char* ldsb = (char*)ldsq;

  int bid = blockIdx.x;
  int mt = bid & 127;
  int nt = bid >> 7;
  int tid = threadIdx.x, w = tid >> 6, l = tid & 63;
  int lr = l & 15, lg = l >> 4;

  int rS = tid >> 3;
  int cSw = (((tid & 7) * 16) ^ ((rS & 7) << 4)) >> 1;

  const ushort* Abase = attn + ((size_t)mt*64)*EE;
  const ushort* Bbase = Wob + ((size_t)nt*128)*EE;

#define OSTAGE(bufidx, kt) do {                                                  \
    char* LA_ = ldsb + (bufidx)*24576;                                           \
    char* LB_ = LA_ + 8192;                                                      \
    const ushort* asrc = Abase + (kt)*64 + cSw;                                  \
    const ushort* bsrc = Bbase + (kt)*64 + cSw;                                  \
    gl2lds(asrc + (size_t)rS*EE,        LA_ + tid*16);                           \
    gl2lds(asrc + (size_t)(rS+32)*EE,   LA_ + 4096 + tid*16);                    \
    gl2lds(bsrc + (size_t)rS*EE,        LB_ + tid*16);                           \
    gl2lds(bsrc + (size_t)(rS+32)*EE,   LB_ + 4096 + tid*16);                    \
    gl2lds(bsrc + (size_t)(rS+64)*EE,   LB_ + 8192 + tid*16);                    \
    gl2lds(bsrc + (size_t)(rS+96)*EE,   LB_ + 12288 + tid*16);                   \
  } while (0)

  f32x4 acc[4][2] = {};

#define OCOMPUTE(bufidx) do {                                                    \
    const char* LA_ = ldsb + (bufidx)*24576;                                     \
    const char* LB_ = LA_ + 8192;                                                \
    bf16x8 af[4][2], bf[2][2];                                                   \
    _Pragma("unroll")                                                            \
    for (int f = 0; f < 4; ++f) {                                                \
      int row = f*16 + lr; int sw = (row & 7) << 4;                              \
      af[f][0] = *(const bf16x8*)(LA_ + row*128 + ((lg*16) ^ sw));               \
      af[f][1] = *(const bf16x8*)(LA_ + row*128 + ((64 + lg*16) ^ sw));          \
    }                                                                            \
    _Pragma("unroll")                                                            \
    for (int g = 0; g < 2; ++g) {                                                \
      int row = w*32 + g*16 + lr; int sw = (row & 7) << 4;                       \
      bf[g][0] = *(const bf16x8*)(LB_ + row*128 + ((lg*16) ^ sw));               \
      bf[g][1] = *(const bf16x8*)(LB_ + row*128 + ((64 + lg*16) ^ sw));          \
    }                                                                            \
    _Pragma("unroll")                                                            \
    for (int f = 0; f < 4; ++f) {                                                \
      _Pragma("unroll")                                                          \
      for (int g = 0; g < 2; ++g) {                                              \
        acc[f][g] = MFMA16(af[f][0], bf[g][0], acc[f][g]);                       \
        acc[f][g] = MFMA16(af[f][1], bf[g][1], acc[f][g]);                       \
      }                                                                          \
    }                                                                            \
  } while (0)

  OSTAGE(0, 0);
  for (int kt = 0; kt < EE/64; ++kt) {
    if (kt < EE/64 - 1) OSTAGE((kt + 1) & 1, kt + 1);
    if (kt < EE/64 - 1) { asm volatile("s_waitcnt vmcnt(6)" ::: "memory"); }
    else                { asm volatile("s_waitcnt vmcnt(0)" ::: "memory"); }
    __builtin_amdgcn_s_barrier();          // all waves' tile-kt loads landed
    __builtin_amdgcn_sched_barrier(0);
    OCOMPUTE(kt & 1);
    __builtin_amdgcn_s_barrier();          // reads done before next iter's OSTAGE
    __builtin_amdgcn_sched_barrier(0);
  }
#undef OSTAGE
#undef OCOMPUTE

#pragma unroll
  for (int g = 0; g < 2; ++g) {
    int col = nt*128 + w*32 + g*16 + lr;
    float bias = bo[col];
#pragma unroll
    for (int f = 0; f < 4; ++f) {
#pragma unroll
      for (int j = 0; j < 4; ++j) {
        int row = mt*64 + f*16 + lg*4 + j;
        out[(size_t)row*EE + col] = acc[f][g][j] + bias;
      }
    }
  }
}

extern "C" void kernel_launch(void* const* d_in, const int* in_sizes, int n_in,
                              void* d_out, int out_size, void* d_ws, size_t ws_size,
                              hipStream_t stream) {
  (void)in_sizes; (void)n_in; (void)out_size; (void)ws_size;
  const float* q  = (const float*)d_in[0];
  const float* k  = (const float*)d_in[1];
  const float* v  = (const float*)d_in[2];
  const float* Wq = (const float*)d_in[3];
  const float* Wk = (const float*)d_in[4];
  const float* Wv = (const float*)d_in[5];
  const float* Wo = (const float*)d_in[6];
  const float* bo = (const float*)d_in[7];
  float* out = (float*)d_out;

  char* ws = (char*)d_ws;
  const size_t SZ = (size_t)BB*HH*SS*DD*2;     // 12582912 bytes each
  ushort* Qb   = (ushort*)(ws);
  ushort* Kb   = (ushort*)(ws + SZ);
  ushort* Vt   = (ushort*)(ws + 2*SZ);
  ushort* attn = (ushort*)(ws + 3*SZ);
  ushort* Wqb  = (ushort*)(ws + 4*SZ);
  ushort* Wkb  = (ushort*)(ws + 4*SZ +   98304);
  ushort* Wvb  = (ushort*)(ws + 4*SZ + 2*98304);
  ushort* Wob  = (ushort*)(ws + 4*SZ + 3*98304);

  cvt_weights<<<(EE*EE + 255)/256, 256, 0, stream>>>(Wq, Wk, Wv, Wo, Wqb, Wkb, Wvb, Wob);
  proj_qkv<<<3*BB*HH*(SS/64), 256, 0, stream>>>(q, k, v, Wqb, Wkb, Wvb, Qb, Kb, Vt);
  attn_fwd<<<BB*HH*(SS/128), 256, 0, stream>>>(Qb, Kb, Vt, attn);
  out_proj<<<(NT/64)*(EE/128), 256, 0, stream>>>(attn, Wob, bo, out);
}

// Round 13
// 82.530 us; speedup vs baseline: 1.2588x; 1.0882x over previous
//
#include <hip/hip_runtime.h>
#include <hip/hip_bf16.h>

#define BB 8
#define SS 1024
#define EE 768
#define HH 12
#define DD 64
#define NT (BB*SS)

typedef __attribute__((ext_vector_type(8))) short bf16x8;
typedef __attribute__((ext_vector_type(4))) float f32x4;

__device__ __forceinline__ ushort f2bf(float f) {
  union { float f; unsigned u; } x; x.f = f;
  unsigned r = x.u + 0x7fffu + ((x.u >> 16) & 1u);
  return (ushort)(r >> 16);
}

// hardware packed f32x2 -> bf16x2 (RNE)
__device__ __forceinline__ unsigned cvtpk(float a, float b) {
  unsigned r;
  asm("v_cvt_pk_bf16_f32 %0, %1, %2" : "=v"(r) : "v"(a), "v"(b));
  return r;
}

__device__ __forceinline__ void gl2lds(const void* g, void* l) {
  __builtin_amdgcn_global_load_lds(
      (const __attribute__((address_space(1))) unsigned int*)g,
      (__attribute__((address_space(3))) unsigned int*)l, 16, 0, 0);
}

#define MFMA16(A, B, C) __builtin_amdgcn_mfma_f32_16x16x32_bf16((A), (B), (C), 0, 0, 0)

// ---------------- weight conversion (all four weight matrices) ----------------
__global__ void cvt_weights(const float* __restrict__ Wq, const float* __restrict__ Wk,
                            const float* __restrict__ Wv, const float* __restrict__ Wo,
                            ushort* __restrict__ Wqb, ushort* __restrict__ Wkb,
                            ushort* __restrict__ Wvb, ushort* __restrict__ Wob) {
  int i = blockIdx.x * blockDim.x + threadIdx.x;
  const int NW = HH*DD*DD;           // 49152
  if (i < NW) { Wqb[i] = f2bf(Wq[i]); Wkb[i] = f2bf(Wk[i]); Wvb[i] = f2bf(Wv[i]); }
  if (i < EE*EE) Wob[i] = f2bf(Wo[i]);
}

// ---------------- QKV projection (4 tiles/block, W reuse, reg-prefetch pipeline) --------
// Grid 3*96*4. Each block: one (m, bh), four 64-row s-tiles. W fragments loaded once;
// X(t+1) prefetched into registers while MFMA(t)+store(t) execute (hides HBM latency).
// Q,K out: [B,H,S,D] bf16 (Q pre-scaled by log2(e)/8); swapped-operand mfma(W,X) ->
//   lane lr owns srow, d = f*16+lg*4+j -> ushort4 stores.
// V out: [B,H,D,S] bf16, transposed + sigma-permuted per 64-k tile:
//   pos = st*64 + 32*(w>>1) + 8*lg + 4*(w&1) + j.
__global__ __launch_bounds__(256) void proj_qkv(
    const float* __restrict__ q, const float* __restrict__ k, const float* __restrict__ v,
    const ushort* __restrict__ Wqb, const ushort* __restrict__ Wkb, const ushort* __restrict__ Wvb,
    ushort* __restrict__ Qb, ushort* __restrict__ Kb, ushort* __restrict__ Vt) {
  int bid = blockIdx.x;
  int m  = bid / (BB*HH*4);        // 0..2
  int r  = bid % (BB*HH*4);
  int bh = r % (BB*HH);            // same-bh blocks differ by 96 == 0 (mod 8) -> same XCD
  int tg = r / (BB*HH);            // 0..3
  int b = bh / HH, h = bh % HH;

  int tid = threadIdx.x;
  int w = tid >> 6, l = tid & 63;
  int lr = l & 15, lg = l >> 4;

  const float*  xbase = (m==0 ? q : (m==1 ? k : v))
                      + ((size_t)(b*SS + tg*256 + w*16 + lr))*EE + h*DD;
  const ushort* W = (m==0 ? Wqb : (m==1 ? Wkb : Wvb)) + h*DD*DD;

  // W fragments: row f*16+lr, k = ks*32 + lg*8 (loaded once, reused for 4 tiles)
  bf16x8 wb0[4], wb1[4];
#pragma unroll
  for (int f = 0; f < 4; ++f) {
    wb0[f] = *(const bf16x8*)(W + (f*16 + lr)*DD + lg*8);
    wb1[f] = *(const bf16x8*)(W + (f*16 + lr)*DD + 32 + lg*8);
  }

  // prefetch X tile 0 (4x f32x4 per thread)
  f32x4 nx0 = *(const f32x4*)(xbase + lg*8);
  f32x4 nx1 = *(const f32x4*)(xbase + lg*8 + 4);
  f32x4 nx2 = *(const f32x4*)(xbase + 32 + lg*8);
  f32x4 nx3 = *(const f32x4*)(xbase + 36 + lg*8);

  float qscale = (m == 0) ? 0.18033688011112042f : 1.0f;  // 0.125*log2(e)

#pragma unroll
  for (int t = 0; t < 4; ++t) {
    f32x4 c0 = nx0, c1 = nx1, c2 = nx2, c3 = nx3;
    if (t < 3) {
      const float* xn = xbase + (size_t)(t + 1)*64*EE;
      nx0 = *(const f32x4*)(xn + lg*8);
      nx1 = *(const f32x4*)(xn + lg*8 + 4);
      nx2 = *(const f32x4*)(xn + 32 + lg*8);
      nx3 = *(const f32x4*)(xn + 36 + lg*8);
    }
    union { bf16x8 v; unsigned u[4]; } a0, a1;
    a0.u[0] = cvtpk(c0[0], c0[1]); a0.u[1] = cvtpk(c0[2], c0[3]);
    a0.u[2] = cvtpk(c1[0], c1[1]); a0.u[3] = cvtpk(c1[2], c1[3]);
    a1.u[0] = cvtpk(c2[0], c2[1]); a1.u[1] = cvtpk(c2[2], c2[3]);
    a1.u[2] = cvtpk(c3[0], c3[1]); a1.u[3] = cvtpk(c3[2], c3[3]);

    f32x4 acc[4] = {};
    int st = tg*4 + t;
    if (m == 2) {
      // V: original order mfma(X, W) -> C[row=srow][col=d]
#pragma unroll
      for (int f = 0; f < 4; ++f) {
        acc[f] = MFMA16(a0.v, wb0[f], acc[f]);
        acc[f] = MFMA16(a1.v, wb1[f], acc[f]);
      }
      int posb = st*64 + 32*(w>>1) + 8*lg + 4*(w&1);
#pragma unroll
      for (int f = 0; f < 4; ++f) {
        ushort2 p0, p1;
        *(unsigned*)&p0 = cvtpk(acc[f][0], acc[f][1]);
        *(unsigned*)&p1 = cvtpk(acc[f][2], acc[f][3]);
        ushort4 pk; pk.x = p0.x; pk.y = p0.y; pk.z = p1.x; pk.w = p1.y;
        *(ushort4*)(Vt + ((size_t)bh*DD + f*16 + lr)*SS + posb) = pk;
      }
    } else {
      // Q/K: swapped order mfma(W, X) -> C[row=d][col=srow]; lane lr owns one srow
#pragma unroll
      for (int f = 0; f < 4; ++f) {
        acc[f] = MFMA16(wb0[f], a0.v, acc[f]);
        acc[f] = MFMA16(wb1[f], a1.v, acc[f]);
      }
      ushort* dst = (m == 0 ? Qb : Kb) + ((size_t)bh*SS + st*64 + w*16 + lr)*DD;
#pragma unroll
      for (int f = 0; f < 4; ++f) {
        ushort2 p0, p1;
        *(unsigned*)&p0 = cvtpk(acc[f][0]*qscale, acc[f][1]*qscale);
        *(unsigned*)&p1 = cvtpk(acc[f][2]*qscale, acc[f][3]*qscale);
        ushort4 pk; pk.x = p0.x; pk.y = p0.y; pk.z = p1.x; pk.w = p1.y;
        *(ushort4*)(dst + f*16 + lg*4) = pk;
      }
    }
  }
}

// ---------------- flash attention (R9 structure, slim 40KB LDS: K 3-deep, V 2-deep) -----
// Block: one (b,h,qtile128). 4 waves x 32 q-rows (dual-Q). P = exp2(S') unshifted;
// normalize in epilogue. bh = bid % 96 -> blocks sharing K/V sit on one XCD.
// Issue order per iter: V(kt+1) then K(kt+2) -> at bar1 the newest 2 loads are K(kt+2),
// so vmcnt(2) guarantees K(kt), V(kt), K(kt+1) landed. 40KB -> 4 blocks/CU (50% occ).
// Denominator l via all-ones-A MFMA (column sums of P, accumulated across tiles).
__global__ __launch_bounds__(256) void attn_fwd(
    const ushort* __restrict__ Qb, const ushort* __restrict__ Kb,
    const ushort* __restrict__ Vt, ushort* __restrict__ attn) {
  __shared__ uint4 ldsq[2560];     // 40 KiB: K bufs 0/8K/16K, V bufs 24K/32K
  char* ldsb = (char*)ldsq;

  int bid = blockIdx.x;
  int bh = bid % (BB*HH);
  int qt = bid / (BB*HH);
  int b = bh / HH, h = bh % HH;
  int tid = threadIdx.x, w = tid >> 6, l = tid & 63;
  int lr = l & 15, lg = l >> 4;

  const ushort* Qp0 = Qb + ((size_t)bh*SS + qt*128 + w*32 + lr)*DD;
  bf16x8 bq[2][2];
  bq[0][0] = *(const bf16x8*)(Qp0 + lg*8);
  bq[0][1] = *(const bf16x8*)(Qp0 + 32 + lg*8);
  bq[1][0] = *(const bf16x8*)(Qp0 + 16*DD + lg*8);
  bq[1][1] = *(const bf16x8*)(Qp0 + 16*DD + 32 + lg*8);

  const ushort* Kbh = Kb + (size_t)bh*SS*DD;
  const ushort* Vbh = Vt + (size_t)bh*DD*SS;

  const short ONE = (short)0x3F80;           // bf16 1.0
  bf16x8 ones = {ONE, ONE, ONE, ONE, ONE, ONE, ONE, ONE};

  f32x4 lsum[2] = {};              // every row = full denominator for col q=lr
  f32x4 o[2][4] = {};

#define STAGE_K(kbuf, kt) do {                                                   \
    char* KB_ = ldsb + (kbuf)*8192;                                              \
    const ushort* ksrc = Kbh + ((size_t)((kt)*64 + w*16 + lr))*DD + lg*8;        \
    gl2lds(ksrc,      KB_ + tid*16);                                             \
    gl2lds(ksrc + 32, KB_ + 4096 + tid*16);                                      \
  } while (0)
#define STAGE_V(vbuf, kt) do {                                                   \
    char* VB_ = ldsb + 24576 + (vbuf)*8192;                                      \
    const ushort* vsrc = Vbh + ((size_t)(w*16 + lr))*SS + (kt)*64 + lg*8;        \
    gl2lds(vsrc,      VB_ + tid*16);                                             \
    gl2lds(vsrc + 32, VB_ + 4096 + tid*16);                                      \
  } while (0)

  STAGE_K(0, 0);
  STAGE_V(0, 0);
  STAGE_K(1, 1);
  int kbuf = 0, vbuf = 0;
  for (int kt = 0; kt < 16; ++kt) {
    const char* KB_ = ldsb + kbuf*8192;
    const char* VB_ = ldsb + 24576 + vbuf*8192;

    // K(kt), V(kt), K(kt+1) landed; the newest 2 (K(kt+2)) may remain in flight
    if (kt < 15) { asm volatile("s_waitcnt vmcnt(2)" ::: "memory"); }
    else         { asm volatile("s_waitcnt vmcnt(0)" ::: "memory"); }
    __builtin_amdgcn_s_barrier();
    __builtin_amdgcn_sched_barrier(0);

    // issue V first, then K (vmcnt counting relies on this order)
    if (kt < 15) STAGE_V(vbuf ^ 1, kt + 1);
    if (kt < 14) { int nk = kbuf + 2; if (nk >= 3) nk -= 3; STAGE_K(nk, kt + 2); }

    f32x4 st0[4] = {}, st1[4] = {};
    __builtin_amdgcn_s_setprio(1);
#pragma unroll
    for (int f = 0; f < 4; ++f) {
      bf16x8 k0 = *(const bf16x8*)(KB_ + f*1024 + l*16);
      bf16x8 k1 = *(const bf16x8*)(KB_ + 4096 + f*1024 + l*16);
      st0[f] = MFMA16(k0, bq[0][0], st0[f]);
      st0[f] = MFMA16(k1, bq[0][1], st0[f]);
      st1[f] = MFMA16(k0, bq[1][0], st1[f]);
      st1[f] = MFMA16(k1, bq[1][1], st1[f]);
    }
    __builtin_amdgcn_s_setprio(0);

    union { bf16x8 v; unsigned u[4]; } pba[2], pbb[2];
#pragma unroll
    for (int s = 0; s < 2; ++s) {
      f32x4* st = (s == 0) ? st0 : st1;
#pragma unroll
      for (int f = 0; f < 4; ++f) {
#pragma unroll
        for (int j = 0; j < 4; ++j) st[f][j] = __builtin_amdgcn_exp2f(st[f][j]);
      }
      pba[s].u[0] = cvtpk(st[0][0], st[0][1]); pba[s].u[1] = cvtpk(st[0][2], st[0][3]);
      pba[s].u[2] = cvtpk(st[1][0], st[1][1]); pba[s].u[3] = cvtpk(st[1][2], st[1][3]);
      pbb[s].u[0] = cvtpk(st[2][0], st[2][1]); pbb[s].u[1] = cvtpk(st[2][2], st[2][3]);
      pbb[s].u[2] = cvtpk(st[3][0], st[3][1]); pbb[s].u[3] = cvtpk(st[3][2], st[3][3]);
    }

    __builtin_amdgcn_s_setprio(1);
#pragma unroll
    for (int f = 0; f < 4; ++f) {
      bf16x8 va = *(const bf16x8*)(VB_ + f*1024 + l*16);          // k-pos 0..31 (sigma)
      bf16x8 vc = *(const bf16x8*)(VB_ + 4096 + f*1024 + l*16);   // k-pos 32..63
      o[0][f] = MFMA16(va, pba[0].v, o[0][f]);
      o[0][f] = MFMA16(vc, pbb[0].v, o[0][f]);
      o[1][f] = MFMA16(va, pba[1].v, o[1][f]);
      o[1][f] = MFMA16(vc, pbb[1].v, o[1][f]);
    }
    // denominator: ones-row MFMA accumulates column sums of P
    lsum[0] = MFMA16(ones, pba[0].v, lsum[0]);
    lsum[0] = MFMA16(ones, pbb[0].v, lsum[0]);
    lsum[1] = MFMA16(ones, pba[1].v, lsum[1]);
    lsum[1] = MFMA16(ones, pbb[1].v, lsum[1]);
    __builtin_amdgcn_s_setprio(0);

    kbuf = (kbuf == 2) ? 0 : kbuf + 1;
    vbuf ^= 1;
  }
#undef STAGE_K
#undef STAGE_V

  // epilogue: lane lr already holds the full denominator for its q in lsum[s][*]
#pragma unroll
  for (int s = 0; s < 2; ++s) {
    float inv = 1.0f / lsum[s][0];
    ushort* orow = attn + ((size_t)(b*SS + qt*128 + w*32 + s*16 + lr))*EE + h*DD;
#pragma unroll
    for (int f = 0; f < 4; ++f) {
      ushort4 pkd;
      pkd.x = f2bf(o[s][f][0] * inv);
      pkd.y = f2bf(o[s][f][1] * inv);
      pkd.z = f2bf(o[s][f][2] * inv);
      pkd.w = f2bf(o[s][f][3] * inv);
      *(ushort4*)(orow + f*16 + lg*4) = pkd;
    }
  }
}

// ---------------- output projection (counted-vmcnt LDS-staged MFMA GEMM) ----------------
// Same-mt blocks congruent mod 8 -> same XCD. Two barriers/iter, vmcnt(6) counted:
// next tile's 6 loads stay in flight across bar1 (no drain-before-barrier stall).
__global__ __launch_bounds__(256) void out_proj(
    const ushort* __restrict__ attn, const ushort* __restrict__ Wob,
    const float* __restrict__ bo, float* __restrict__ out) {
  __shared__ uint4 ldsq[3072];   // 48 KiB: 2 buffers x (A 8KB + B 16KB)
  char* ldsb = (char*)ldsq;

  int bid = blockIdx.x;
  int mt = bid & 127;
  int nt = bid >> 7;
  int tid = threadIdx.x, w = tid >> 6, l = tid & 63;
  int lr = l & 15, lg = l >> 4;

  int rS = tid >> 3;
  int cSw = (((tid & 7) * 16) ^ ((rS & 7) << 4)) >> 1;

  const ushort* Abase = attn + ((size_t)mt*64)*EE;
  const ushort* Bbase = Wob + ((size_t)nt*128)*EE;

#define OSTAGE(bufidx, kt) do {                                                  \
    char* LA_ = ldsb + (bufidx)*24576;                                           \
    char* LB_ = LA_ + 8192;                                                      \
    const ushort* asrc = Abase + (kt)*64 + cSw;                                  \
    const ushort* bsrc = Bbase + (kt)*64 + cSw;                                  \
    gl2lds(asrc + (size_t)rS*EE,        LA_ + tid*16);                           \
    gl2lds(asrc + (size_t)(rS+32)*EE,   LA_ + 4096 + tid*16);                    \
    gl2lds(bsrc + (size_t)rS*EE,        LB_ + tid*16);                           \
    gl2lds(bsrc + (size_t)(rS+32)*EE,   LB_ + 4096 + tid*16);                    \
    gl2lds(bsrc + (size_t)(rS+64)*EE,   LB_ + 8192 + tid*16);                    \
    gl2lds(bsrc + (size_t)(rS+96)*EE,   LB_ + 12288 + tid*16);                   \
  } while (0)

  f32x4 acc[4][2] = {};

#define OCOMPUTE(bufidx) do {                                                    \
    const char* LA_ = ldsb + (bufidx)*24576;                                     \
    const char* LB_ = LA_ + 8192;                                                \
    bf16x8 af[4][2], bf[2][2];                                                   \
    _Pragma("unroll")                                                            \
    for (int f = 0; f < 4; ++f) {                                                \
      int row = f*16 + lr; int sw = (row & 7) << 4;                              \
      af[f][0] = *(const bf16x8*)(LA_ + row*128 + ((lg*16) ^ sw));               \
      af[f][1] = *(const bf16x8*)(LA_ + row*128 + ((64 + lg*16) ^ sw));          \
    }                                                                            \
    _Pragma("unroll")                                                            \
    for (int g = 0; g < 2; ++g) {                                                \
      int row = w*32 + g*16 + lr; int sw = (row & 7) << 4;                       \
      bf[g][0] = *(const bf16x8*)(LB_ + row*128 + ((lg*16) ^ sw));               \
      bf[g][1] = *(const bf16x8*)(LB_ + row*128 + ((64 + lg*16) ^ sw));          \
    }                                                                            \
    _Pragma("unroll")                                                            \
    for (int f = 0; f < 4; ++f) {                                                \
      _Pragma("unroll")                                                          \
      for (int g = 0; g < 2; ++g) {                                              \
        acc[f][g] = MFMA16(af[f][0], bf[g][0], acc[f][g]);                       \
        acc[f][g] = MFMA16(af[f][1], bf[g][1], acc[f][g]);                       \
      }                                                                          \
    }                                                                            \
  } while (0)

  OSTAGE(0, 0);
  for (int kt = 0; kt < EE/64; ++kt) {
    if (kt < EE/64 - 1) OSTAGE((kt + 1) & 1, kt + 1);
    if (kt < EE/64 - 1) { asm volatile("s_waitcnt vmcnt(6)" ::: "memory"); }
    else                { asm volatile("s_waitcnt vmcnt(0)" ::: "memory"); }
    __builtin_amdgcn_s_barrier();          // all waves' tile-kt loads landed
    __builtin_amdgcn_sched_barrier(0);
    OCOMPUTE(kt & 1);
    __builtin_amdgcn_s_barrier();          // reads done before next iter's OSTAGE
    __builtin_amdgcn_sched_barrier(0);
  }
#undef OSTAGE
#undef OCOMPUTE

#pragma unroll
  for (int g = 0; g < 2; ++g) {
    int col = nt*128 + w*32 + g*16 + lr;
    float bias = bo[col];
#pragma unroll
    for (int f = 0; f < 4; ++f) {
#pragma unroll
      for (int j = 0; j < 4; ++j) {
        int row = mt*64 + f*16 + lg*4 + j;
        out[(size_t)row*EE + col] = acc[f][g][j] + bias;
      }
    }
  }
}

extern "C" void kernel_launch(void* const* d_in, const int* in_sizes, int n_in,
                              void* d_out, int out_size, void* d_ws, size_t ws_size,
                              hipStream_t stream) {
  (void)in_sizes; (void)n_in; (void)out_size; (void)ws_size;
  const float* q  = (const float*)d_in[0];
  const float* k  = (const float*)d_in[1];
  const float* v  = (const float*)d_in[2];
  const float* Wq = (const float*)d_in[3];
  const float* Wk = (const float*)d_in[4];
  const float* Wv = (const float*)d_in[5];
  const float* Wo = (const float*)d_in[6];
  const float* bo = (const float*)d_in[7];
  float* out = (float*)d_out;

  char* ws = (char*)d_ws;
  const size_t SZ = (size_t)BB*HH*SS*DD*2;     // 12582912 bytes each
  ushort* Qb   = (ushort*)(ws);
  ushort* Kb   = (ushort*)(ws + SZ);
  ushort* Vt   = (ushort*)(ws + 2*SZ);
  ushort* attn = (ushort*)(ws + 3*SZ);
  ushort* Wqb  = (ushort*)(ws + 4*SZ);
  ushort* Wkb  = (ushort*)(ws + 4*SZ +   98304);
  ushort* Wvb  = (ushort*)(ws + 4*SZ + 2*98304);
  ushort* Wob  = (ushort*)(ws + 4*SZ + 3*98304);

  cvt_weights<<<(EE*EE + 255)/256, 256, 0, stream>>>(Wq, Wk, Wv, Wo, Wqb, Wkb, Wvb, Wob);
  proj_qkv<<<3*BB*HH*4, 256, 0, stream>>>(q, k, v, Wqb, Wkb, Wvb, Qb, Kb, Vt);
  attn_fwd<<<BB*HH*(SS/128), 256, 0, stream>>>(Qb, Kb, Vt, attn);
  out_proj<<<(NT/64)*(EE/128), 256, 0, stream>>>(attn, Wob, bo, out);
}

// Round 16
// 79.479 us; speedup vs baseline: 1.3071x; 1.0384x over previous
//
#include <hip/hip_runtime.h>
#include <hip/hip_bf16.h>

#define BB 8
#define SS 1024
#define EE 768
#define HH 12
#define DD 64
#define NT (BB*SS)

typedef __attribute__((ext_vector_type(8))) short bf16x8;
typedef __attribute__((ext_vector_type(4))) float f32x4;

__device__ __forceinline__ ushort f2bf(float f) {
  union { float f; unsigned u; } x; x.f = f;
  unsigned r = x.u + 0x7fffu + ((x.u >> 16) & 1u);
  return (ushort)(r >> 16);
}

// hardware packed f32x2 -> bf16x2 (RNE)
__device__ __forceinline__ unsigned cvtpk(float a, float b) {
  unsigned r;
  asm("v_cvt_pk_bf16_f32 %0, %1, %2" : "=v"(r) : "v"(a), "v"(b));
  return r;
}

__device__ __forceinline__ void gl2lds(const void* g, void* l) {
  __builtin_amdgcn_global_load_lds(
      (const __attribute__((address_space(1))) unsigned int*)g,
      (__attribute__((address_space(3))) unsigned int*)l, 16, 0, 0);
}

#define MFMA16(A, B, C) __builtin_amdgcn_mfma_f32_16x16x32_bf16((A), (B), (C), 0, 0, 0)

// ---------------- QKV projection + Wo conversion (cvt_weights launch eliminated) --------
// Blocks [0, 1152): projection. One (m, bh, tile-group of 4 s-tiles). W converted inline
//   from f32 ONCE per block (amortized over 4 tiles; R11's regression was per-tile reload).
//   X register pipeline 2 tiles deep: prologue loads tiles 0,1; iter t computes t,
//   prefetches t+2. Pure register pipeline, compile-time indices, no sync.
// Blocks [1152, 1440): convert Wo f32 -> bf16 (Wob read only by out_proj, 2 launches later).
// Q,K out: [B,H,S,D] bf16 (Q pre-scaled by log2(e)/8); swapped-operand mfma(W,X).
// V out: [B,H,D,S] bf16, transposed + sigma-permuted per 64-k tile:
//   pos = st*64 + 32*(w>>1) + 8*lg + 4*(w&1) + j.
__global__ __launch_bounds__(256) void proj_qkv(
    const float* __restrict__ q, const float* __restrict__ k, const float* __restrict__ v,
    const float* __restrict__ Wq, const float* __restrict__ Wk, const float* __restrict__ Wv,
    const float* __restrict__ Wo,
    ushort* __restrict__ Qb, ushort* __restrict__ Kb, ushort* __restrict__ Vt,
    ushort* __restrict__ Wob) {
  int bid = blockIdx.x;
  int tid = threadIdx.x;

  if (bid >= 3*BB*HH*4) {
    // ---- Wo conversion: 288 blocks x 2048 elements ----
    int i = (bid - 3*BB*HH*4) * 2048 + tid * 8;
    f32x4 w0 = *(const f32x4*)(Wo + i);
    f32x4 w1 = *(const f32x4*)(Wo + i + 4);
    uint4 pk;
    pk.x = cvtpk(w0[0], w0[1]);
    pk.y = cvtpk(w0[2], w0[3]);
    pk.z = cvtpk(w1[0], w1[1]);
    pk.w = cvtpk(w1[2], w1[3]);
    *(uint4*)(Wob + i) = pk;
    return;
  }

  int m  = bid / (BB*HH*4);        // 0..2
  int r  = bid % (BB*HH*4);
  int bh = r % (BB*HH);            // same-bh blocks differ by 96 == 0 (mod 8) -> same XCD
  int tg = r / (BB*HH);            // 0..3
  int b = bh / HH, h = bh % HH;

  int w = tid >> 6, l = tid & 63;
  int lr = l & 15, lg = l >> 4;

  const float* xbase = (m==0 ? q : (m==1 ? k : v))
                     + ((size_t)(b*SS + tg*256 + w*16 + lr))*EE + h*DD;
  const float* Wf = (m==0 ? Wq : (m==1 ? Wk : Wv)) + h*DD*DD;

  // W fragments converted inline ONCE per block: row f*16+lr, k = ks*32 + lg*8
  bf16x8 wb0[4], wb1[4];
#pragma unroll
  for (int f = 0; f < 4; ++f) {
    const float* wr = Wf + (f*16 + lr)*DD + lg*8;
    f32x4 u0 = *(const f32x4*)(wr);      f32x4 u1 = *(const f32x4*)(wr + 4);
    f32x4 u2 = *(const f32x4*)(wr + 32); f32x4 u3 = *(const f32x4*)(wr + 36);
    union { bf16x8 v; unsigned u[4]; } t0, t1;
    t0.u[0] = cvtpk(u0[0], u0[1]); t0.u[1] = cvtpk(u0[2], u0[3]);
    t0.u[2] = cvtpk(u1[0], u1[1]); t0.u[3] = cvtpk(u1[2], u1[3]);
    t1.u[0] = cvtpk(u2[0], u2[1]); t1.u[1] = cvtpk(u2[2], u2[3]);
    t1.u[2] = cvtpk(u3[0], u3[1]); t1.u[3] = cvtpk(u3[2], u3[3]);
    wb0[f] = t0.v; wb1[f] = t1.v;
  }

  // X register pipeline, 2 tiles deep (indices compile-time under full unroll)
  f32x4 px[2][4];
#pragma unroll
  for (int d = 0; d < 2; ++d) {
    const float* xn = xbase + (size_t)d*64*EE;
    px[d][0] = *(const f32x4*)(xn + lg*8);
    px[d][1] = *(const f32x4*)(xn + lg*8 + 4);
    px[d][2] = *(const f32x4*)(xn + 32 + lg*8);
    px[d][3] = *(const f32x4*)(xn + 36 + lg*8);
  }

  float qscale = (m == 0) ? 0.18033688011112042f : 1.0f;  // 0.125*log2(e)

#pragma unroll
  for (int t = 0; t < 4; ++t) {
    f32x4 c0 = px[t&1][0], c1 = px[t&1][1], c2 = px[t&1][2], c3 = px[t&1][3];
    if (t < 2) {
      const float* xn = xbase + (size_t)(t + 2)*64*EE;
      px[t&1][0] = *(const f32x4*)(xn + lg*8);
      px[t&1][1] = *(const f32x4*)(xn + lg*8 + 4);
      px[t&1][2] = *(const f32x4*)(xn + 32 + lg*8);
      px[t&1][3] = *(const f32x4*)(xn + 36 + lg*8);
    }
    union { bf16x8 v; unsigned u[4]; } a0, a1;
    a0.u[0] = cvtpk(c0[0], c0[1]); a0.u[1] = cvtpk(c0[2], c0[3]);
    a0.u[2] = cvtpk(c1[0], c1[1]); a0.u[3] = cvtpk(c1[2], c1[3]);
    a1.u[0] = cvtpk(c2[0], c2[1]); a1.u[1] = cvtpk(c2[2], c2[3]);
    a1.u[2] = cvtpk(c3[0], c3[1]); a1.u[3] = cvtpk(c3[2], c3[3]);

    f32x4 acc[4] = {};
    int st = tg*4 + t;
    if (m == 2) {
      // V: original order mfma(X, W) -> C[row=srow][col=d]
#pragma unroll
      for (int f = 0; f < 4; ++f) {
        acc[f] = MFMA16(a0.v, wb0[f], acc[f]);
        acc[f] = MFMA16(a1.v, wb1[f], acc[f]);
      }
      int posb = st*64 + 32*(w>>1) + 8*lg + 4*(w&1);
#pragma unroll
      for (int f = 0; f < 4; ++f) {
        ushort2 p0, p1;
        *(unsigned*)&p0 = cvtpk(acc[f][0], acc[f][1]);
        *(unsigned*)&p1 = cvtpk(acc[f][2], acc[f][3]);
        ushort4 pk; pk.x = p0.x; pk.y = p0.y; pk.z = p1.x; pk.w = p1.y;
        *(ushort4*)(Vt + ((size_t)bh*DD + f*16 + lr)*SS + posb) = pk;
      }
    } else {
      // Q/K: swapped order mfma(W, X) -> C[row=d][col=srow]; lane lr owns one srow
#pragma unroll
      for (int f = 0; f < 4; ++f) {
        acc[f] = MFMA16(wb0[f], a0.v, acc[f]);
        acc[f] = MFMA16(wb1[f], a1.v, acc[f]);
      }
      ushort* dst = (m == 0 ? Qb : Kb) + ((size_t)bh*SS + st*64 + w*16 + lr)*DD;
#pragma unroll
      for (int f = 0; f < 4; ++f) {
        ushort2 p0, p1;
        *(unsigned*)&p0 = cvtpk(acc[f][0]*qscale, acc[f][1]*qscale);
        *(unsigned*)&p1 = cvtpk(acc[f][2]*qscale, acc[f][3]*qscale);
        ushort4 pk; pk.x = p0.x; pk.y = p0.y; pk.z = p1.x; pk.w = p1.y;
        *(ushort4*)(dst + f*16 + lg*4) = pk;
      }
    }
  }
}

// ---------------- flash attention (R13-verified: ROLLED loop — do not unroll) ----------
// Three correctness failures (R10/R14/R15) came from enlarging this loop's scheduling
// region (ITER pipeline / full unroll, even with sched_barrier fences). Rolled form is
// the verified anchor. Block: one (b,h,qtile128). 4 waves x 32 q-rows (dual-Q).
// P = exp2(S') unshifted; normalize in epilogue. bh = bid % 96 -> same-XCD K/V share.
// K 3-deep / V 2-deep LDS buffers; issue order V(kt+1) then K(kt+2); vmcnt(2) at top.
// Denominator l via all-ones-A MFMA (column sums of P, accumulated across tiles).
__global__ __launch_bounds__(256) void attn_fwd(
    const ushort* __restrict__ Qb, const ushort* __restrict__ Kb,
    const ushort* __restrict__ Vt, ushort* __restrict__ attn) {
  __shared__ uint4 ldsq[2560];     // 40 KiB: K bufs 0/8K/16K, V bufs 24K/32K
  char* ldsb = (char*)ldsq;

  int bid = blockIdx.x;
  int bh = bid % (BB*HH);
  int qt = bid / (BB*HH);
  int b = bh / HH, h = bh % HH;
  int tid = threadIdx.x, w = tid >> 6, l = tid & 63;
  int lr = l & 15, lg = l >> 4;

  const ushort* Qp0 = Qb + ((size_t)bh*SS + qt*128 + w*32 + lr)*DD;
  bf16x8 bq[2][2];
  bq[0][0] = *(const bf16x8*)(Qp0 + lg*8);
  bq[0][1] = *(const bf16x8*)(Qp0 + 32 + lg*8);
  bq[1][0] = *(const bf16x8*)(Qp0 + 16*DD + lg*8);
  bq[1][1] = *(const bf16x8*)(Qp0 + 16*DD + 32 + lg*8);

  const ushort* Kbh = Kb + (size_t)bh*SS*DD;
  const ushort* Vbh = Vt + (size_t)bh*DD*SS;

  const short ONE = (short)0x3F80;           // bf16 1.0
  bf16x8 ones = {ONE, ONE, ONE, ONE, ONE, ONE, ONE, ONE};

  f32x4 lsum[2] = {};              // every row = full denominator for col q=lr
  f32x4 o[2][4] = {};

#define STAGE_K(kbuf, kt) do {                                                   \
    char* KB_ = ldsb + (kbuf)*8192;                                              \
    const ushort* ksrc = Kbh + ((size_t)((kt)*64 + w*16 + lr))*DD + lg*8;        \
    gl2lds(ksrc,      KB_ + tid*16);                                             \
    gl2lds(ksrc + 32, KB_ + 4096 + tid*16);                                      \
  } while (0)
#define STAGE_V(vbuf, kt) do {                                                   \
    char* VB_ = ldsb + 24576 + (vbuf)*8192;                                      \
    const ushort* vsrc = Vbh + ((size_t)(w*16 + lr))*SS + (kt)*64 + lg*8;        \
    gl2lds(vsrc,      VB_ + tid*16);                                             \
    gl2lds(vsrc + 32, VB_ + 4096 + tid*16);                                      \
  } while (0)

  STAGE_K(0, 0);
  STAGE_V(0, 0);
  STAGE_K(1, 1);
  int kbuf = 0, vbuf = 0;
  for (int kt = 0; kt < 16; ++kt) {
    const char* KB_ = ldsb + kbuf*8192;
    const char* VB_ = ldsb + 24576 + vbuf*8192;

    // K(kt), V(kt), K(kt+1) landed; the newest 2 (K(kt+2)) may remain in flight
    if (kt < 15) { asm volatile("s_waitcnt vmcnt(2)" ::: "memory"); }
    else         { asm volatile("s_waitcnt vmcnt(0)" ::: "memory"); }
    __builtin_amdgcn_s_barrier();
    __builtin_amdgcn_sched_barrier(0);

    // issue V first, then K (vmcnt counting relies on this order)
    if (kt < 15) STAGE_V(vbuf ^ 1, kt + 1);
    if (kt < 14) { int nk = kbuf + 2; if (nk >= 3) nk -= 3; STAGE_K(nk, kt + 2); }

    f32x4 st0[4] = {}, st1[4] = {};
    __builtin_amdgcn_s_setprio(1);
#pragma unroll
    for (int f = 0; f < 4; ++f) {
      bf16x8 k0 = *(const bf16x8*)(KB_ + f*1024 + l*16);
      bf16x8 k1 = *(const bf16x8*)(KB_ + 4096 + f*1024 + l*16);
      st0[f] = MFMA16(k0, bq[0][0], st0[f]);
      st0[f] = MFMA16(k1, bq[0][1], st0[f]);
      st1[f] = MFMA16(k0, bq[1][0], st1[f]);
      st1[f] = MFMA16(k1, bq[1][1], st1[f]);
    }
    __builtin_amdgcn_s_setprio(0);

    union { bf16x8 v; unsigned u[4]; } pba[2], pbb[2];
#pragma unroll
    for (int s = 0; s < 2; ++s) {
      f32x4* st = (s == 0) ? st0 : st1;
#pragma unroll
      for (int f = 0; f < 4; ++f) {
#pragma unroll
        for (int j = 0; j < 4; ++j) st[f][j] = __builtin_amdgcn_exp2f(st[f][j]);
      }
      pba[s].u[0] = cvtpk(st[0][0], st[0][1]); pba[s].u[1] = cvtpk(st[0][2], st[0][3]);
      pba[s].u[2] = cvtpk(st[1][0], st[1][1]); pba[s].u[3] = cvtpk(st[1][2], st[1][3]);
      pbb[s].u[0] = cvtpk(st[2][0], st[2][1]); pbb[s].u[1] = cvtpk(st[2][2], st[2][3]);
      pbb[s].u[2] = cvtpk(st[3][0], st[3][1]); pbb[s].u[3] = cvtpk(st[3][2], st[3][3]);
    }

    __builtin_amdgcn_s_setprio(1);
#pragma unroll
    for (int f = 0; f < 4; ++f) {
      bf16x8 va = *(const bf16x8*)(VB_ + f*1024 + l*16);          // k-pos 0..31 (sigma)
      bf16x8 vc = *(const bf16x8*)(VB_ + 4096 + f*1024 + l*16);   // k-pos 32..63
      o[0][f] = MFMA16(va, pba[0].v, o[0][f]);
      o[0][f] = MFMA16(vc, pbb[0].v, o[0][f]);
      o[1][f] = MFMA16(va, pba[1].v, o[1][f]);
      o[1][f] = MFMA16(vc, pbb[1].v, o[1][f]);
    }
    // denominator: ones-row MFMA accumulates column sums of P
    lsum[0] = MFMA16(ones, pba[0].v, lsum[0]);
    lsum[0] = MFMA16(ones, pbb[0].v, lsum[0]);
    lsum[1] = MFMA16(ones, pba[1].v, lsum[1]);
    lsum[1] = MFMA16(ones, pbb[1].v, lsum[1]);
    __builtin_amdgcn_s_setprio(0);

    kbuf = (kbuf == 2) ? 0 : kbuf + 1;
    vbuf ^= 1;
  }
#undef STAGE_K
#undef STAGE_V

  // epilogue: lane lr already holds the full denominator for its q in lsum[s][*]
#pragma unroll
  for (int s = 0; s < 2; ++s) {
    float inv = 1.0f / lsum[s][0];
    ushort* orow = attn + ((size_t)(b*SS + qt*128 + w*32 + s*16 + lr))*EE + h*DD;
#pragma unroll
    for (int f = 0; f < 4; ++f) {
      ushort4 pkd;
      pkd.x = f2bf(o[s][f][0] * inv);
      pkd.y = f2bf(o[s][f][1] * inv);
      pkd.z = f2bf(o[s][f][2] * inv);
      pkd.w = f2bf(o[s][f][3] * inv);
      *(ushort4*)(orow + f*16 + lg*4) = pkd;
    }
  }
}

// ---------------- output projection (counted-vmcnt LDS-staged MFMA GEMM) ----------------
// Same-mt blocks congruent mod 8 -> same XCD. Two barriers/iter, vmcnt(6) counted:
// next tile's 6 loads stay in flight across bar1 (no drain-before-barrier stall).
__global__ __launch_bounds__(256) void out_proj(
    const ushort* __restrict__ attn, const ushort* __restrict__ Wob,
    const float* __restrict__ bo, float* __restrict__ out) {
  __shared__ uint4 ldsq[3072];   // 48 KiB: 2 buffers x (A 8KB + B 16KB)
  char* ldsb = (char*)ldsq;

  int bid = blockIdx.x;
  int mt = bid & 127;
  int nt = bid >> 7;
  int tid = threadIdx.x, w = tid >> 6, l = tid & 63;
  int lr = l & 15, lg = l >> 4;

  int rS = tid >> 3;
  int cSw = (((tid & 7) * 16) ^ ((rS & 7) << 4)) >> 1;

  const ushort* Abase = attn + ((size_t)mt*64)*EE;
  const ushort* Bbase = Wob + ((size_t)nt*128)*EE;

#define OSTAGE(bufidx, kt) do {                                                  \
    char* LA_ = ldsb + (bufidx)*24576;                                           \
    char* LB_ = LA_ + 8192;                                                      \
    const ushort* asrc = Abase + (kt)*64 + cSw;                                  \
    const ushort* bsrc = Bbase + (kt)*64 + cSw;                                  \
    gl2lds(asrc + (size_t)rS*EE,        LA_ + tid*16);                           \
    gl2lds(asrc + (size_t)(rS+32)*EE,   LA_ + 4096 + tid*16);                    \
    gl2lds(bsrc + (size_t)rS*EE,        LB_ + tid*16);                           \
    gl2lds(bsrc + (size_t)(rS+32)*EE,   LB_ + 4096 + tid*16);                    \
    gl2lds(bsrc + (size_t)(rS+64)*EE,   LB_ + 8192 + tid*16);                    \
    gl2lds(bsrc + (size_t)(rS+96)*EE,   LB_ + 12288 + tid*16);                   \
  } while (0)

  f32x4 acc[4][2] = {};

#define OCOMPUTE(bufidx) do {                                                    \
    const char* LA_ = ldsb + (bufidx)*24576;                                     \
    const char* LB_ = LA_ + 8192;                                                \
    bf16x8 af[4][2], bf[2][2];                                                   \
    _Pragma("unroll")                                                            \
    for (int f = 0; f < 4; ++f) {                                                \
      int row = f*16 + lr; int sw = (row & 7) << 4;                              \
      af[f][0] = *(const bf16x8*)(LA_ + row*128 + ((lg*16) ^ sw));               \
      af[f][1] = *(const bf16x8*)(LA_ + row*128 + ((64 + lg*16) ^ sw));          \
    }                                                                            \
    _Pragma("unroll")                                                            \
    for (int g = 0; g < 2; ++g) {                                                \
      int row = w*32 + g*16 + lr; int sw = (row & 7) << 4;                       \
      bf[g][0] = *(const bf16x8*)(LB_ + row*128 + ((lg*16) ^ sw));               \
      bf[g][1] = *(const bf16x8*)(LB_ + row*128 + ((64 + lg*16) ^ sw));          \
    }                                                                            \
    _Pragma("unroll")                                                            \
    for (int f = 0; f < 4; ++f) {                                                \
      _Pragma("unroll")                                                          \
      for (int g = 0; g < 2; ++g) {                                              \
        acc[f][g] = MFMA16(af[f][0], bf[g][0], acc[f][g]);                       \
        acc[f][g] = MFMA16(af[f][1], bf[g][1], acc[f][g]);                       \
      }                                                                          \
    }                                                                            \
  } while (0)

  OSTAGE(0, 0);
  for (int kt = 0; kt < EE/64; ++kt) {
    if (kt < EE/64 - 1) OSTAGE((kt + 1) & 1, kt + 1);
    if (kt < EE/64 - 1) { asm volatile("s_waitcnt vmcnt(6)" ::: "memory"); }
    else                { asm volatile("s_waitcnt vmcnt(0)" ::: "memory"); }
    __builtin_amdgcn_s_barrier();          // all waves' tile-kt loads landed
    __builtin_amdgcn_sched_barrier(0);
    OCOMPUTE(kt & 1);
    __builtin_amdgcn_s_barrier();          // reads done before next iter's OSTAGE
    __builtin_amdgcn_sched_barrier(0);
  }
#undef OSTAGE
#undef OCOMPUTE

#pragma unroll
  for (int g = 0; g < 2; ++g) {
    int col = nt*128 + w*32 + g*16 + lr;
    float bias = bo[col];
#pragma unroll
    for (int f = 0; f < 4; ++f) {
#pragma unroll
      for (int j = 0; j < 4; ++j) {
        int row = mt*64 + f*16 + lg*4 + j;
        out[(size_t)row*EE + col] = acc[f][g][j] + bias;
      }
    }
  }
}

extern "C" void kernel_launch(void* const* d_in, const int* in_sizes, int n_in,
                              void* d_out, int out_size, void* d_ws, size_t ws_size,
                              hipStream_t stream) {
  (void)in_sizes; (void)n_in; (void)out_size; (void)ws_size;
  const float* q  = (const float*)d_in[0];
  const float* k  = (const float*)d_in[1];
  const float* v  = (const float*)d_in[2];
  const float* Wq = (const float*)d_in[3];
  const float* Wk = (const float*)d_in[4];
  const float* Wv = (const float*)d_in[5];
  const float* Wo = (const float*)d_in[6];
  const float* bo = (const float*)d_in[7];
  float* out = (float*)d_out;

  char* ws = (char*)d_ws;
  const size_t SZ = (size_t)BB*HH*SS*DD*2;     // 12582912 bytes each
  ushort* Qb   = (ushort*)(ws);
  ushort* Kb   = (ushort*)(ws + SZ);
  ushort* Vt   = (ushort*)(ws + 2*SZ);
  ushort* attn = (ushort*)(ws + 3*SZ);
  ushort* Wob  = (ushort*)(ws + 4*SZ);

  proj_qkv<<<3*BB*HH*4 + (EE*EE)/2048, 256, 0, stream>>>(
      q, k, v, Wq, Wk, Wv, Wo, Qb, Kb, Vt, Wob);
  attn_fwd<<<BB*HH*(SS/128), 256, 0, stream>>>(Qb, Kb, Vt, attn);
  out_proj<<<(NT/64)*(EE/128), 256, 0, stream>>>(attn, Wob, bo, out);
}